// Round 4
// baseline (66.020 us; speedup 1.0000x reference)
//
#include <hip/hip_runtime.h>
#include <math.h>

namespace {

constexpr int D  = 256;
constexpr int H  = 8;

// ---------------- Kernel 1: qW[bn,h,e] = sum_d q[bn,d] * W[h,d,e] ----------------
__global__ __launch_bounds__(256) void qw_kernel(
    const float* __restrict__ q, const float* __restrict__ W,
    float* __restrict__ qW) {
  __shared__ float qT[256][20];
  const int tid = threadIdx.x;
  const int bn0 = blockIdx.x * 16;
  const int h   = blockIdx.y;
  for (int i = 0; i < 16; ++i)
    qT[tid][i] = q[(size_t)(bn0 + i) * D + tid];
  __syncthreads();

  const int r0 = (tid >> 6) << 2;
  const int e0 = (tid & 63) << 2;
  float acc[4][4];
  #pragma unroll
  for (int r = 0; r < 4; ++r)
    #pragma unroll
    for (int e = 0; e < 4; ++e) acc[r][e] = 0.f;

  const float4* W4 = reinterpret_cast<const float4*>(W + (size_t)h * D * D);
  const int ecol = e0 >> 2;
  for (int d = 0; d < D; ++d) {
    float4 qv = *reinterpret_cast<const float4*>(&qT[d][r0]);
    float4 wv = W4[d * 64 + ecol];
    const float qa[4] = {qv.x, qv.y, qv.z, qv.w};
    const float wa[4] = {wv.x, wv.y, wv.z, wv.w};
    #pragma unroll
    for (int r = 0; r < 4; ++r)
      #pragma unroll
      for (int e = 0; e < 4; ++e)
        acc[r][e] += qa[r] * wa[e];
  }
  #pragma unroll
  for (int r = 0; r < 4; ++r) {
    float4 o = make_float4(acc[r][0], acc[r][1], acc[r][2], acc[r][3]);
    *reinterpret_cast<float4*>(&qW[(size_t)(bn0 + r0 + r) * (H * D) + h * D + e0]) = o;
  }
}

// ---------------- Kernel 2: scores + chunk-softmax -> attn ----------------
// Chunk c of the reshape-softmax covers flat [64c,64c+64) = k rows [8c,8c+8),
// so scores/softmax split cleanly by k-halves. Grid (bn=1024, kh=2), 256 thr.
// Thread -> one score (krow = 32*kh + (tid>>3), h = tid&7); k batched 8-deep.
__global__ __launch_bounds__(256, 8) void score_kernel(
    const float* __restrict__ qW, const float* __restrict__ kin,
    const float* __restrict__ bin, float* __restrict__ attn_out) {
  __shared__ float qW_lds[H][260];
  __shared__ float s_lds[256];      // 32 local k-rows x 8 h, flat krl*8+h
  const int tid = threadIdx.x;
  const int bn  = blockIdx.x;
  const int kh  = blockIdx.y;
  const int wid = tid >> 6;
  const int ln  = tid & 63;

  // stage qW (8 x 256) coalesced
  const float4* qw4 = reinterpret_cast<const float4*>(qW) + (size_t)bn * 512;
  {
    float4 q0 = qw4[tid];
    float4 q1 = qw4[tid + 256];
    *reinterpret_cast<float4*>(&qW_lds[tid >> 6][(tid & 63) << 2]) = q0;
    *reinterpret_cast<float4*>(&qW_lds[(tid + 256) >> 6][(tid & 63) << 2]) = q1;
  }
  __syncthreads();

  // scores
  {
    const int krl = tid >> 3;       // 0..31 (local row)
    const int h   = tid & 7;
    const float4* k4 = reinterpret_cast<const float4*>(kin) +
                       (size_t)bn * 4096 + (size_t)(kh * 32 + krl) * 64;
    const float4* a4 = reinterpret_cast<const float4*>(&qW_lds[h][0]);
    float acc = bin[h];
    for (int blk = 0; blk < 8; ++blk) {
      float4 kb[8];
      #pragma unroll
      for (int j = 0; j < 8; ++j) kb[j] = k4[blk * 8 + j];
      #pragma unroll
      for (int j = 0; j < 8; ++j) {
        float4 a = a4[blk * 8 + j];
        acc += a.x * kb[j].x + a.y * kb[j].y + a.z * kb[j].z + a.w * kb[j].w;
      }
    }
    s_lds[krl * 8 + h] = acc;
  }
  __syncthreads();

  // softmax: wave wid owns chunk c = 4*kh + wid (local flat [wid*64, +64))
  {
    float x = s_lds[wid * 64 + ln];
    float m = x;
    #pragma unroll
    for (int off = 32; off; off >>= 1) m = fmaxf(m, __shfl_xor(m, off, 64));
    float e = expf(x - m);
    float s = e;
    #pragma unroll
    for (int off = 32; off; off >>= 1) s += __shfl_xor(s, off, 64);
    attn_out[(size_t)bn * 512 + (4 * kh + wid) * 64 + ln] = e / s;
  }
}

// ---------------- Kernel 3: PV ----------------
// wsum[kk] = sum_{c=0..7} attn[bn][c*64+kk] (read back from d_out, L2-hot);
// out[bn][d] = sum_k wsum[k] * v[bn][k][d]. Grid (bn=1024, dh=2), 256 thr.
__global__ __launch_bounds__(256, 8) void pv_kernel(
    const float* __restrict__ vin, const float* __restrict__ attn_in,
    float* __restrict__ out) {
  __shared__ float ws[64];
  __shared__ float s_red[8][32][4];
  const int tid = threadIdx.x;
  const int bn  = blockIdx.x;
  const int dh  = blockIdx.y;

  if (tid < 64) {
    const float* ap = attn_in + (size_t)bn * 512 + tid;
    float w = 0.f;
    #pragma unroll
    for (int c = 0; c < 8; ++c) w += ap[c * 64];
    ws[tid] = w;
  }
  __syncthreads();

  const int d4 = tid & 31;          // float4 col within this d-half
  const int rg = tid >> 5;          // row group 0..7
  const float4* v4 = reinterpret_cast<const float4*>(vin) +
                     (size_t)bn * 4096 + dh * 32;
  float4 vv[8];
  #pragma unroll
  for (int i = 0; i < 8; ++i) vv[i] = v4[(size_t)(rg + i * 8) * 64 + d4];
  float4 acc = make_float4(0.f, 0.f, 0.f, 0.f);
  #pragma unroll
  for (int i = 0; i < 8; ++i) {
    float w = ws[rg + i * 8];
    acc.x += w * vv[i].x; acc.y += w * vv[i].y;
    acc.z += w * vv[i].z; acc.w += w * vv[i].w;
  }
  *reinterpret_cast<float4*>(&s_red[rg][d4][0]) = acc;
  __syncthreads();

  if (tid < 32) {
    float4 o = make_float4(0.f, 0.f, 0.f, 0.f);
    #pragma unroll
    for (int g = 0; g < 8; ++g) {
      float4 r = *reinterpret_cast<const float4*>(&s_red[g][tid][0]);
      o.x += r.x; o.y += r.y; o.z += r.z; o.w += r.w;
    }
    reinterpret_cast<float4*>(out)[(size_t)bn * 64 + dh * 32 + tid] = o;
  }
}

}  // namespace

extern "C" void kernel_launch(void* const* d_in, const int* in_sizes, int n_in,
                              void* d_out, int out_size, void* d_ws, size_t ws_size,
                              hipStream_t stream) {
  const float* q = (const float*)d_in[0];   // (8,128,1,256)
  const float* k = (const float*)d_in[1];   // (8,128,64,256)
  const float* v = (const float*)d_in[2];   // (8,128,64,256)
  const float* W = (const float*)d_in[3];   // (8,256,256)
  const float* b = (const float*)d_in[4];   // (8,)

  float* out  = (float*)d_out;              // output: 262144 f32
  float* attn = out + 262144;               // attn:   524288 f32
  float* qWbuf = (float*)d_ws;              // 1024*2048 f32 = 8 MiB scratch

  hipLaunchKernelGGL(qw_kernel, dim3(64, 8), dim3(256), 0, stream, q, W, qWbuf);
  hipLaunchKernelGGL(score_kernel, dim3(1024, 2), dim3(256), 0, stream,
                     qWbuf, k, b, attn);
  hipLaunchKernelGGL(pv_kernel, dim3(1024, 2), dim3(256), 0, stream,
                     v, attn, out);
}

// Round 5
// 57.860 us; speedup vs baseline: 1.1410x; 1.1410x over previous
//
#include <hip/hip_runtime.h>
#include <math.h>

namespace {

constexpr int D  = 256;
constexpr int H  = 8;

// Async global->LDS, 16B per lane: LDS dest = wave-uniform base + lane*16,
// global src is per-lane (pre-swizzle the source to get swizzled LDS layout).
__device__ inline void async_copy16(float4* lds_dst, const float4* gsrc) {
  __builtin_amdgcn_global_load_lds(
      (const __attribute__((address_space(1))) unsigned int*)(gsrc),
      (__attribute__((address_space(3))) unsigned int*)(lds_dst), 16, 0, 0);
}

// ---------------- Kernel 1: qW[bn,h,e] = sum_d q[bn,d] * W[h,d,e] ----------------
__global__ __launch_bounds__(256) void qw_kernel(
    const float* __restrict__ q, const float* __restrict__ W,
    float* __restrict__ qW) {
  __shared__ float qT[256][20];
  const int tid = threadIdx.x;
  const int bn0 = blockIdx.x * 16;
  const int h   = blockIdx.y;
  for (int i = 0; i < 16; ++i)
    qT[tid][i] = q[(size_t)(bn0 + i) * D + tid];
  __syncthreads();

  const int r0 = (tid >> 6) << 2;
  const int e0 = (tid & 63) << 2;
  float acc[4][4];
  #pragma unroll
  for (int r = 0; r < 4; ++r)
    #pragma unroll
    for (int e = 0; e < 4; ++e) acc[r][e] = 0.f;

  const float4* W4 = reinterpret_cast<const float4*>(W + (size_t)h * D * D);
  const int ecol = e0 >> 2;
  for (int d = 0; d < D; ++d) {
    float4 qv = *reinterpret_cast<const float4*>(&qT[d][r0]);
    float4 wv = W4[d * 64 + ecol];
    const float qa[4] = {qv.x, qv.y, qv.z, qv.w};
    const float wa[4] = {wv.x, wv.y, wv.z, wv.w};
    #pragma unroll
    for (int r = 0; r < 4; ++r)
      #pragma unroll
      for (int e = 0; e < 4; ++e)
        acc[r][e] += qa[r] * wa[e];
  }
  #pragma unroll
  for (int r = 0; r < 4; ++r) {
    float4 o = make_float4(acc[r][0], acc[r][1], acc[r][2], acc[r][3]);
    *reinterpret_cast<float4*>(&qW[(size_t)(bn0 + r0 + r) * (H * D) + h * D + e0]) = o;
  }
}

// ---------------- Kernel 2: scores + chunk-softmax -> attn ----------------
// Grid (bn=1024, kh=2), 256 threads = 4 waves. Wave wid owns softmax chunk
// c = 4*kh + wid = k rows [8c, 8c+8). k staged wave-contiguously into LDS via
// global_load_lds (1 KB/instr), source-swizzled (ln ^ row&7) so compute reads
// are bank-conflict-free. Each lane ends holding score flat-index ln of its
// chunk -> softmax is pure wave shuffles, attn write is 256B contiguous.
__global__ __launch_bounds__(256) void score_kernel(
    const float* __restrict__ qW, const float* __restrict__ kin,
    const float* __restrict__ bin, float* __restrict__ attn_out) {
  __shared__ float4 k_lds[32][64];     // 32 KB, linear rows (gload_lds dest)
  __shared__ float  qW_lds[H][260];    // pad 260: h-rows staggered across banks
  const int tid = threadIdx.x;
  const int bn  = blockIdx.x;
  const int kh  = blockIdx.y;
  const int wid = tid >> 6;
  const int ln  = tid & 63;

  // ---- issue async k stages first: wave wid -> rows wid*8 .. wid*8+7
  const float4* kbase = reinterpret_cast<const float4*>(kin) +
                        (size_t)bn * 4096 + (size_t)(kh * 32 + wid * 8) * 64;
  #pragma unroll
  for (int i = 0; i < 8; ++i) {
    async_copy16(&k_lds[wid * 8 + i][0], kbase + i * 64 + (ln ^ i));
  }

  // ---- stage qW (8 x 256) coalesced; barrier drains the async k loads too
  const float4* qw4 = reinterpret_cast<const float4*>(qW) + (size_t)bn * 512;
  {
    float4 q0 = qw4[tid];
    float4 q1 = qw4[tid + 256];
    *reinterpret_cast<float4*>(&qW_lds[tid >> 6][(tid & 63) << 2]) = q0;
    *reinterpret_cast<float4*>(&qW_lds[(tid + 256) >> 6][(tid & 63) << 2]) = q1;
  }
  __syncthreads();

  // ---- scores: lane ln -> local row rloc = ln>>3, head h = ln&7
  const int rloc = ln >> 3;
  const int h    = ln & 7;
  const float4* a4   = reinterpret_cast<const float4*>(&qW_lds[h][0]);
  const float4* krow = &k_lds[wid * 8 + rloc][0];
  float acc = bin[h];
  #pragma unroll 8
  for (int e = 0; e < 64; ++e) {
    float4 kv = krow[e ^ rloc];        // undo source swizzle
    float4 av = a4[e];
    acc += av.x * kv.x + av.y * kv.y + av.z * kv.z + av.w * kv.w;
  }

  // ---- softmax across the wave (lane ln holds flat element ln of chunk c)
  float m = acc;
  #pragma unroll
  for (int off = 32; off; off >>= 1) m = fmaxf(m, __shfl_xor(m, off, 64));
  float ex = expf(acc - m);
  float s = ex;
  #pragma unroll
  for (int off = 32; off; off >>= 1) s += __shfl_xor(s, off, 64);
  attn_out[(size_t)bn * 512 + (4 * kh + wid) * 64 + ln] = ex / s;
}

// ---------------- Kernel 3: PV ----------------
__global__ __launch_bounds__(256, 8) void pv_kernel(
    const float* __restrict__ vin, const float* __restrict__ attn_in,
    float* __restrict__ out) {
  __shared__ float ws[64];
  __shared__ float s_red[8][32][4];
  const int tid = threadIdx.x;
  const int bn  = blockIdx.x;
  const int dh  = blockIdx.y;

  if (tid < 64) {
    const float* ap = attn_in + (size_t)bn * 512 + tid;
    float w = 0.f;
    #pragma unroll
    for (int c = 0; c < 8; ++c) w += ap[c * 64];
    ws[tid] = w;
  }
  __syncthreads();

  const int d4 = tid & 31;
  const int rg = tid >> 5;
  const float4* v4 = reinterpret_cast<const float4*>(vin) +
                     (size_t)bn * 4096 + dh * 32;
  float4 vv[8];
  #pragma unroll
  for (int i = 0; i < 8; ++i) vv[i] = v4[(size_t)(rg + i * 8) * 64 + d4];
  float4 acc = make_float4(0.f, 0.f, 0.f, 0.f);
  #pragma unroll
  for (int i = 0; i < 8; ++i) {
    float w = ws[rg + i * 8];
    acc.x += w * vv[i].x; acc.y += w * vv[i].y;
    acc.z += w * vv[i].z; acc.w += w * vv[i].w;
  }
  *reinterpret_cast<float4*>(&s_red[rg][d4][0]) = acc;
  __syncthreads();

  if (tid < 32) {
    float4 o = make_float4(0.f, 0.f, 0.f, 0.f);
    #pragma unroll
    for (int g = 0; g < 8; ++g) {
      float4 r = *reinterpret_cast<const float4*>(&s_red[g][tid][0]);
      o.x += r.x; o.y += r.y; o.z += r.z; o.w += r.w;
    }
    reinterpret_cast<float4*>(out)[(size_t)bn * 64 + dh * 32 + tid] = o;
  }
}

}  // namespace

extern "C" void kernel_launch(void* const* d_in, const int* in_sizes, int n_in,
                              void* d_out, int out_size, void* d_ws, size_t ws_size,
                              hipStream_t stream) {
  const float* q = (const float*)d_in[0];   // (8,128,1,256)
  const float* k = (const float*)d_in[1];   // (8,128,64,256)
  const float* v = (const float*)d_in[2];   // (8,128,64,256)
  const float* W = (const float*)d_in[3];   // (8,256,256)
  const float* b = (const float*)d_in[4];   // (8,)

  float* out  = (float*)d_out;              // output: 262144 f32
  float* attn = out + 262144;               // attn:   524288 f32
  float* qWbuf = (float*)d_ws;              // 1024*2048 f32 = 8 MiB scratch

  hipLaunchKernelGGL(qw_kernel, dim3(64, 8), dim3(256), 0, stream, q, W, qWbuf);
  hipLaunchKernelGGL(score_kernel, dim3(1024, 2), dim3(256), 0, stream,
                     qWbuf, k, b, attn);
  hipLaunchKernelGGL(pv_kernel, dim3(1024, 2), dim3(256), 0, stream,
                     v, attn, out);
}